// Round 1
// baseline (851.291 us; speedup 1.0000x reference)
//
#include <hip/hip_runtime.h>
#include <hip/hip_bf16.h>

// Problem constants (fixed by the reference setup_inputs)
constexpr int R  = 4;
constexpr int NN = 10000;   // nodes
constexpr int EE = 2000;    // hyperedges
constexpr int FF = 128;     // in features
constexpr int OO = 128;     // out features
#define EPSV 1e-8f

typedef __attribute__((ext_vector_type(8))) short   bf16x8;  // MFMA A/B frag (8 bf16)
typedef __attribute__((ext_vector_type(4))) float   f32x4;   // MFMA C/D frag

// round-to-nearest-even f32 -> bf16 bits (inputs finite)
__device__ inline unsigned short f2bf(float x) {
    unsigned int u = __float_as_uint(x);
    unsigned int r = (u + 0x7fffu + ((u >> 16) & 1u)) >> 16;
    return (unsigned short)r;
}

// ---------------------------------------------------------------------------
// K1: degrees. Per block: one relation, 16 rows. Row sums -> dv_is = rsqrt(Dv+eps).
// Column partials kept in registers (e = 2*(t+256i)+{0,1}), atomicAdd to De.
// ---------------------------------------------------------------------------
__global__ __launch_bounds__(256) void k_deg(const float* __restrict__ H,
                                             float* __restrict__ dv_is,
                                             float* __restrict__ De) {
    const int r    = blockIdx.y;
    const int row0 = blockIdx.x * 16;       // 625*16 = 10000 exact
    const int t    = threadIdx.x;
    const float* Hr = H + (size_t)r * NN * EE;

    float cax[4] = {0.f, 0.f, 0.f, 0.f};
    float cay[4] = {0.f, 0.f, 0.f, 0.f};
    float rp[16];

    for (int j = 0; j < 16; ++j) {
        const float2* Hrow2 = (const float2*)(Hr + (size_t)(row0 + j) * EE);
        float s = 0.f;
#pragma unroll
        for (int i = 0; i < 4; ++i) {
            int e2 = t + 256 * i;           // float2 index, e = 2*e2
            if (e2 < EE / 2) {
                float2 v = Hrow2[e2];
                s += v.x + v.y;
                cax[i] += v.x;
                cay[i] += v.y;
            }
        }
        rp[j] = s;
    }

    __shared__ float lds[16][257];
#pragma unroll
    for (int j = 0; j < 16; ++j) lds[j][t] = rp[j];
    __syncthreads();
    const int jj = t >> 4, s0 = t & 15;
    float x = 0.f;
#pragma unroll
    for (int k = 0; k < 16; ++k) x += lds[jj][s0 + 16 * k];
    __syncthreads();
    lds[jj][s0] = x;
    __syncthreads();
    if (t < 16) {
        float sum = 0.f;
#pragma unroll
        for (int s = 0; s < 16; ++s) sum += lds[t][s];
        dv_is[r * NN + row0 + t] = rsqrtf(sum + EPSV);
    }

#pragma unroll
    for (int i = 0; i < 4; ++i) {
        int e2 = t + 256 * i;
        if (e2 < EE / 2) {
            atomicAdd(&De[r * EE + 2 * e2 + 0], cax[i]);
            atomicAdd(&De[r * EE + 2 * e2 + 1], cay[i]);
        }
    }
}

// ---------------------------------------------------------------------------
// K2: Xbt[f][n] = bf16(X[n][f])  (transpose so GEMM1's B operand is K-contiguous)
// ---------------------------------------------------------------------------
__global__ __launch_bounds__(256) void k_xt(const float* __restrict__ X,
                                            unsigned short* __restrict__ Xbt) {
    const int n0 = blockIdx.x * 64;
    const int f0 = blockIdx.y * 64;
    __shared__ float tile[64][65];
    const int t = threadIdx.x;
    {
        int nl = t >> 2;              // 0..63
        int fl = (t & 3) * 16;        // 0,16,32,48
        int n  = n0 + nl;
#pragma unroll
        for (int c = 0; c < 4; ++c) {
            float4 v = make_float4(0.f, 0.f, 0.f, 0.f);
            if (n < NN) v = *(const float4*)(X + (size_t)n * FF + f0 + fl + 4 * c);
            tile[nl][fl + 4 * c + 0] = v.x;
            tile[nl][fl + 4 * c + 1] = v.y;
            tile[nl][fl + 4 * c + 2] = v.z;
            tile[nl][fl + 4 * c + 3] = v.w;
        }
    }
    __syncthreads();
    {
        int fr = t >> 2;              // 0..63
        int nc = (t & 3) * 16;        // 0,16,32,48
        unsigned short u[16];
#pragma unroll
        for (int k = 0; k < 16; ++k) u[k] = f2bf(tile[nc + k][fr]);
        int f = f0 + fr;
        int nb = n0 + nc;
        unsigned short* dst = Xbt + (size_t)f * NN + nb;
        if (nb + 15 < NN) {
            uint4 p0, p1;
            p0.x = (unsigned)u[0]  | ((unsigned)u[1]  << 16);
            p0.y = (unsigned)u[2]  | ((unsigned)u[3]  << 16);
            p0.z = (unsigned)u[4]  | ((unsigned)u[5]  << 16);
            p0.w = (unsigned)u[6]  | ((unsigned)u[7]  << 16);
            p1.x = (unsigned)u[8]  | ((unsigned)u[9]  << 16);
            p1.y = (unsigned)u[10] | ((unsigned)u[11] << 16);
            p1.z = (unsigned)u[12] | ((unsigned)u[13] << 16);
            p1.w = (unsigned)u[14] | ((unsigned)u[15] << 16);
            *(uint4*)(dst)     = p0;
            *(uint4*)(dst + 8) = p1;
        } else {
#pragma unroll
            for (int k = 0; k < 16; ++k)
                if (nb + k < NN) dst[k] = u[k];
        }
    }
}

// LDS addressing: row-major rows of 64 bf16 (128B), XOR swizzle on byte bits 4-6
__device__ inline int lds_addr(int row, int byte_col) {
    return row * 128 + (byte_col ^ ((row & 7) << 4));
}

// ---------------------------------------------------------------------------
// K3: GEMM1.  T[r][e][f] = (1/(De+eps)) * sum_n (dv[n]*H[r][n][e]) * X[n][f]
// BM=32 (e), BN=128 (f, 4 waves x 32), BK=64 (n). A transpose-staged from f32 H.
// ---------------------------------------------------------------------------
__global__ __launch_bounds__(256) void k_gemm1(const float* __restrict__ H,
                                               const unsigned short* __restrict__ Xbt,
                                               const float* __restrict__ dv_is,
                                               const float* __restrict__ De,
                                               float* __restrict__ T) {
    const int r  = blockIdx.y;
    const int e0 = blockIdx.x * 32;
    __shared__ unsigned short lA[32 * 64];
    __shared__ unsigned short lB[128 * 64];
    char* lAb = (char*)lA;
    char* lBb = (char*)lB;

    const int t = threadIdx.x;
    const int wave = t >> 6, lane = t & 63;
    const float* Hr  = H + (size_t)r * NN * EE;
    const float* dvr = dv_is + r * NN;

    f32x4 acc[2][2];
#pragma unroll
    for (int m = 0; m < 2; ++m)
#pragma unroll
        for (int n = 0; n < 2; ++n) acc[m][n] = (f32x4){0.f, 0.f, 0.f, 0.f};

    const int eg = (t & 7) * 4;   // A: 4 e-rows per thread
    const int np = t >> 3;        // A: n-pair index 0..31
    const int bf = t >> 1;        // B: f row 0..127
    const int bh = (t & 1) * 32;  // B: half of 64 n

    for (int k0 = 0; k0 < NN; k0 += 64) {
        __syncthreads();
        // ---- stage A (transpose + dv scale + bf16) ----
        {
            int n_ = k0 + 2 * np;
            float va[4] = {0.f, 0.f, 0.f, 0.f};
            float vb[4] = {0.f, 0.f, 0.f, 0.f};
            float d0 = 0.f, d1 = 0.f;
            const int eb = e0 + eg;
            const bool efull = (eb + 3) < EE;
            if (n_ < NN) {
                d0 = dvr[n_];
                const float* p = Hr + (size_t)n_ * EE + eb;
                if (efull) {
                    float4 v = *(const float4*)p;
                    va[0] = v.x; va[1] = v.y; va[2] = v.z; va[3] = v.w;
                } else {
#pragma unroll
                    for (int c = 0; c < 4; ++c)
                        if (eb + c < EE) va[c] = p[c];
                }
            }
            if (n_ + 1 < NN) {
                d1 = dvr[n_ + 1];
                const float* p = Hr + (size_t)(n_ + 1) * EE + eb;
                if (efull) {
                    float4 v = *(const float4*)p;
                    vb[0] = v.x; vb[1] = v.y; vb[2] = v.z; vb[3] = v.w;
                } else {
#pragma unroll
                    for (int c = 0; c < 4; ++c)
                        if (eb + c < EE) vb[c] = p[c];
                }
            }
#pragma unroll
            for (int j = 0; j < 4; ++j) {
                int row = eg + j;
                unsigned pk = (unsigned)f2bf(va[j] * d0) |
                              ((unsigned)f2bf(vb[j] * d1) << 16);
                *(unsigned*)(lAb + lds_addr(row, 4 * np)) = pk;
            }
        }
        // ---- stage B (bf16 copy from Xbt) ----
        {
#pragma unroll
            for (int j2 = 0; j2 < 4; ++j2) {
                int nb = bh + 8 * j2;
                uint4 v = *(const uint4*)(Xbt + (size_t)bf * NN + k0 + nb);
                *(uint4*)(lBb + lds_addr(bf, 2 * nb)) = v;
            }
        }
        __syncthreads();
        // ---- MFMA ----
        {
            const int kb = (lane >> 4) * 16;
#pragma unroll
            for (int kk = 0; kk < 2; ++kk) {
                bf16x8 a[2], b[2];
#pragma unroll
                for (int m = 0; m < 2; ++m) {
                    int row = (lane & 15) + 16 * m;
                    a[m] = *(const bf16x8*)(lAb + lds_addr(row, kk * 64 + kb));
                }
#pragma unroll
                for (int nf = 0; nf < 2; ++nf) {
                    int row = wave * 32 + (lane & 15) + 16 * nf;
                    b[nf] = *(const bf16x8*)(lBb + lds_addr(row, kk * 64 + kb));
                }
#pragma unroll
                for (int m = 0; m < 2; ++m)
#pragma unroll
                    for (int nf = 0; nf < 2; ++nf)
                        acc[m][nf] = __builtin_amdgcn_mfma_f32_16x16x32_bf16(
                            a[m], b[nf], acc[m][nf], 0, 0, 0);
            }
        }
    }
    // ---- epilogue: scale by de^2 = 1/(De+eps), store T ----
#pragma unroll
    for (int m = 0; m < 2; ++m) {
        int e_b = e0 + 16 * m + (lane >> 4) * 4;
#pragma unroll
        for (int j = 0; j < 4; ++j) {
            int e = e_b + j;
            if (e < EE) {
                float de2 = 1.0f / (De[r * EE + e] + EPSV);
#pragma unroll
                for (int nf = 0; nf < 2; ++nf) {
                    int f = wave * 32 + 16 * nf + (lane & 15);
                    T[((size_t)r * EE + e) * FF + f] = acc[m][nf][j] * de2;
                }
            }
        }
    }
}

// ---------------------------------------------------------------------------
// K4: V^T[r][o][e] = bf16( sigmoid(ri[r]) * sum_f T[r][e][f] * W[r][f][o] )
// f32 accumulate; tiny GEMM (K=128).
// ---------------------------------------------------------------------------
__global__ __launch_bounds__(256) void k_v(const float* __restrict__ T,
                                           const float* __restrict__ W,
                                           const float* __restrict__ ri,
                                           unsigned short* __restrict__ Vt) {
    const int r  = blockIdx.y;
    const int e0 = blockIdx.x * 32;
    const float gate = 1.f / (1.f + expf(-ri[r]));
    __shared__ float lT[32][129];
    const int t = threadIdx.x;
    {
        int el = t >> 3, fl = (t & 7) * 16;
        int e = e0 + el;
#pragma unroll
        for (int c = 0; c < 4; ++c) {
            float4 v = make_float4(0.f, 0.f, 0.f, 0.f);
            if (e < EE) v = *(const float4*)(T + ((size_t)r * EE + e) * FF + fl + 4 * c);
            lT[el][fl + 4 * c + 0] = v.x;
            lT[el][fl + 4 * c + 1] = v.y;
            lT[el][fl + 4 * c + 2] = v.z;
            lT[el][fl + 4 * c + 3] = v.w;
        }
    }
    __syncthreads();
    const int o  = t & 127;
    const int eh = t >> 7;
    float acc[16];
#pragma unroll
    for (int k = 0; k < 16; ++k) acc[k] = 0.f;
    const float* Wr = W + (size_t)r * FF * OO + o;
#pragma unroll 4
    for (int f = 0; f < FF; ++f) {
        float w = Wr[(size_t)f * OO];
#pragma unroll
        for (int k = 0; k < 16; ++k) acc[k] += lT[eh * 16 + k][f] * w;
    }
    const int ebase = e0 + eh * 16;
    unsigned short* dst = Vt + ((size_t)r * OO + o) * EE + ebase;
    if (ebase + 15 < EE) {
        unsigned short u[16];
#pragma unroll
        for (int k = 0; k < 16; ++k) u[k] = f2bf(gate * acc[k]);
        uint4 p0, p1;
        p0.x = (unsigned)u[0]  | ((unsigned)u[1]  << 16);
        p0.y = (unsigned)u[2]  | ((unsigned)u[3]  << 16);
        p0.z = (unsigned)u[4]  | ((unsigned)u[5]  << 16);
        p0.w = (unsigned)u[6]  | ((unsigned)u[7]  << 16);
        p1.x = (unsigned)u[8]  | ((unsigned)u[9]  << 16);
        p1.y = (unsigned)u[10] | ((unsigned)u[11] << 16);
        p1.z = (unsigned)u[12] | ((unsigned)u[13] << 16);
        p1.w = (unsigned)u[14] | ((unsigned)u[15] << 16);
        *(uint4*)(dst)     = p0;
        *(uint4*)(dst + 8) = p1;
    } else {
#pragma unroll
        for (int k = 0; k < 16; ++k)
            if (ebase + k < EE) dst[k] = f2bf(gate * acc[k]);
    }
}

// ---------------------------------------------------------------------------
// K5: GEMM2.  out[n][o] = bias[o] + sum_r sum_e (dv*H)[r][n][e] * Vt[r][o][e]
// BM=16 (n), BN=128 (o, 4 waves x 32), BK=64 (e); r-loop fused inside.
// ---------------------------------------------------------------------------
__global__ __launch_bounds__(256) void k_gemm2(const float* __restrict__ H,
                                               const unsigned short* __restrict__ Vt,
                                               const float* __restrict__ dv_is,
                                               const float* __restrict__ bias,
                                               float* __restrict__ out) {
    const int n0 = blockIdx.x * 16;   // 625*16 = 10000 exact
    __shared__ unsigned short lA[16 * 64];
    __shared__ unsigned short lB[128 * 64];
    char* lAb = (char*)lA;
    char* lBb = (char*)lB;

    const int t = threadIdx.x;
    const int wave = t >> 6, lane = t & 63;

    f32x4 acc[2];
    acc[0] = (f32x4){0.f, 0.f, 0.f, 0.f};
    acc[1] = (f32x4){0.f, 0.f, 0.f, 0.f};

    const int nl  = t >> 4;          // A: n row 0..15
    const int el4 = (t & 15) * 4;    // A: 4 e per thread
    const int bo  = t >> 1;          // B: o row 0..127
    const int bh  = (t & 1) * 32;    // B: half of 64 e

    for (int r = 0; r < R; ++r) {
        const float* Hrow = H + ((size_t)r * NN + n0 + nl) * EE;
        const float dv = dv_is[r * NN + n0 + nl];
        const unsigned short* Vtr = Vt + (size_t)r * OO * EE;

        for (int ek = 0; ek < 2048; ek += 64) {   // 32 steps covering E=2000
            __syncthreads();
            // ---- stage A (dv scale + bf16) ----
            {
                int e = ek + el4;
                float va[4] = {0.f, 0.f, 0.f, 0.f};
                if (e + 3 < EE) {
                    float4 v = *(const float4*)(Hrow + e);
                    va[0] = v.x; va[1] = v.y; va[2] = v.z; va[3] = v.w;
                } else {
#pragma unroll
                    for (int c = 0; c < 4; ++c)
                        if (e + c < EE) va[c] = Hrow[e + c];
                }
                uint2 pk;
                pk.x = (unsigned)f2bf(va[0] * dv) | ((unsigned)f2bf(va[1] * dv) << 16);
                pk.y = (unsigned)f2bf(va[2] * dv) | ((unsigned)f2bf(va[3] * dv) << 16);
                *(uint2*)(lAb + lds_addr(nl, 2 * el4)) = pk;
            }
            // ---- stage B (bf16 copy from Vt) ----
            {
#pragma unroll
                for (int j2 = 0; j2 < 4; ++j2) {
                    int ebo = bh + 8 * j2;
                    uint4 v = *(const uint4*)(Vtr + (size_t)bo * EE + ek + ebo);
                    *(uint4*)(lBb + lds_addr(bo, 2 * ebo)) = v;
                }
            }
            __syncthreads();
            // ---- MFMA ----
            {
                const int kb = (lane >> 4) * 16;
#pragma unroll
                for (int kk = 0; kk < 2; ++kk) {
                    int arow = lane & 15;
                    bf16x8 a = *(const bf16x8*)(lAb + lds_addr(arow, kk * 64 + kb));
#pragma unroll
                    for (int nf = 0; nf < 2; ++nf) {
                        int row = wave * 32 + (lane & 15) + 16 * nf;
                        bf16x8 b = *(const bf16x8*)(lBb + lds_addr(row, kk * 64 + kb));
                        acc[nf] = __builtin_amdgcn_mfma_f32_16x16x32_bf16(
                            a, b, acc[nf], 0, 0, 0);
                    }
                }
            }
        }
    }
    // ---- epilogue ----
    {
        int nrow = n0 + (lane >> 4) * 4;
#pragma unroll
        for (int nf = 0; nf < 2; ++nf) {
            int o = wave * 32 + 16 * nf + (lane & 15);
            float bv = bias[o];
#pragma unroll
            for (int j = 0; j < 4; ++j)
                out[(size_t)(nrow + j) * OO + o] = acc[nf][j] + bv;
        }
    }
}

// ---------------------------------------------------------------------------
extern "C" void kernel_launch(void* const* d_in, const int* in_sizes, int n_in,
                              void* d_out, int out_size, void* d_ws, size_t ws_size,
                              hipStream_t stream) {
    const float* X    = (const float*)d_in[0];
    const float* H    = (const float*)d_in[1];
    const float* W    = (const float*)d_in[2];
    const float* ri   = (const float*)d_in[3];
    const float* bias = (const float*)d_in[4];
    float* out = (float*)d_out;

    char* ws = (char*)d_ws;
    size_t off = 0;
    auto alloc = [&](size_t bytes) {
        size_t o = off;
        off += (bytes + 1023) & ~(size_t)1023;
        return o;
    };
    float*          dv_is = (float*)(ws + alloc((size_t)R * NN * 4));
    float*          De    = (float*)(ws + alloc((size_t)R * EE * 4));
    unsigned short* Xbt   = (unsigned short*)(ws + alloc((size_t)FF * NN * 2 + 4096));
    float*          T     = (float*)(ws + alloc((size_t)R * EE * FF * 4));
    unsigned short* Vt    = (unsigned short*)(ws + alloc((size_t)R * OO * EE * 2 + 4096));

    hipMemsetAsync(De, 0, (size_t)R * EE * 4, stream);

    hipLaunchKernelGGL(k_deg,   dim3(NN / 16, R),            dim3(256), 0, stream, H, dv_is, De);
    hipLaunchKernelGGL(k_xt,    dim3((NN + 63) / 64, FF / 64), dim3(256), 0, stream, X, Xbt);
    hipLaunchKernelGGL(k_gemm1, dim3((EE + 31) / 32, R),     dim3(256), 0, stream, H, Xbt, dv_is, De, T);
    hipLaunchKernelGGL(k_v,     dim3((EE + 31) / 32, R),     dim3(256), 0, stream, T, W, ri, Vt);
    hipLaunchKernelGGL(k_gemm2, dim3(NN / 16),               dim3(256), 0, stream, H, Vt, dv_is, bias, out);
}

// Round 3
// 732.148 us; speedup vs baseline: 1.1627x; 1.1627x over previous
//
#include <hip/hip_runtime.h>
#include <hip/hip_bf16.h>

// Problem constants (fixed by the reference setup_inputs)
constexpr int R  = 4;
constexpr int NN = 10000;   // nodes
constexpr int EE = 2000;    // hyperedges
constexpr int FF = 128;     // in features
constexpr int OO = 128;     // out features
constexpr int NBLK = 625;   // prep blocks per relation (16 rows each)
#define EPSV 1e-8f

typedef __attribute__((ext_vector_type(8))) short   bf16x8;  // MFMA A/B frag (8 bf16)
typedef __attribute__((ext_vector_type(4))) float   f32x4;   // MFMA C/D frag

// round-to-nearest-even f32 -> bf16 bits (inputs finite)
__device__ inline unsigned short f2bf(float x) {
    unsigned int u = __float_as_uint(x);
    return (unsigned short)((u + 0x7fffu + ((u >> 16) & 1u)) >> 16);
}

// LDS addressing: row-major rows of 64 bf16 (128B), XOR swizzle on byte bits 4-6
__device__ inline int lds_addr(int row, int byte_col) {
    return row * 128 + (byte_col ^ ((row & 7) << 4));
}

// ---------------------------------------------------------------------------
// K1 prep: per (r, 16-row block): read f32 H once; write Hb = bf16(H);
// row sums -> dv_is = rsqrt(Dv+eps); per-block column partials -> Dep (no atomics).
// ---------------------------------------------------------------------------
__global__ __launch_bounds__(256) void k_prep(const float* __restrict__ H,
                                              unsigned short* __restrict__ Hb,
                                              float* __restrict__ dv_is,
                                              float* __restrict__ Dep) {
    const int r = blockIdx.y, blk = blockIdx.x, row0 = blk * 16;
    const int t = threadIdx.x;
    const float* Hr = H + ((size_t)r * NN + row0) * EE;
    unsigned short* Hbr = Hb + ((size_t)r * NN + row0) * EE;

    float cp[8] = {0.f, 0.f, 0.f, 0.f, 0.f, 0.f, 0.f, 0.f};
    float rp[16];

    for (int j = 0; j < 16; ++j) {
        const float4* src = (const float4*)(Hr + (size_t)j * EE);
        unsigned short* dstrow = Hbr + (size_t)j * EE;
        float s = 0.f;
        {   // i = 0: float4 index t (always < 500)
            float4 v = src[t];
            s += v.x + v.y + v.z + v.w;
            cp[0] += v.x; cp[1] += v.y; cp[2] += v.z; cp[3] += v.w;
            uint2 pk;
            pk.x = (unsigned)f2bf(v.x) | ((unsigned)f2bf(v.y) << 16);
            pk.y = (unsigned)f2bf(v.z) | ((unsigned)f2bf(v.w) << 16);
            *(uint2*)(dstrow + 4 * t) = pk;
        }
        if (t < 244) {   // i = 1: float4 index t+256 < 500
            float4 v = src[t + 256];
            s += v.x + v.y + v.z + v.w;
            cp[4] += v.x; cp[5] += v.y; cp[6] += v.z; cp[7] += v.w;
            uint2 pk;
            pk.x = (unsigned)f2bf(v.x) | ((unsigned)f2bf(v.y) << 16);
            pk.y = (unsigned)f2bf(v.z) | ((unsigned)f2bf(v.w) << 16);
            *(uint2*)(dstrow + 4 * (t + 256)) = pk;
        }
        rp[j] = s;
    }

    __shared__ float lds[16][257];
#pragma unroll
    for (int j = 0; j < 16; ++j) lds[j][t] = rp[j];
    __syncthreads();
    const int jj = t >> 4, s0 = t & 15;
    float x = 0.f;
#pragma unroll
    for (int k = 0; k < 16; ++k) x += lds[jj][s0 + 16 * k];
    __syncthreads();
    lds[jj][s0] = x;
    __syncthreads();
    if (t < 16) {
        float sum = 0.f;
#pragma unroll
        for (int s = 0; s < 16; ++s) sum += lds[t][s];
        dv_is[r * NN + row0 + t] = rsqrtf(sum + EPSV);
    }

    float* Dp = Dep + (size_t)(r * NBLK + blk) * EE;
    *(float4*)(Dp + 4 * t) = make_float4(cp[0], cp[1], cp[2], cp[3]);
    if (t < 244)
        *(float4*)(Dp + 4 * (t + 256)) = make_float4(cp[4], cp[5], cp[6], cp[7]);
}

// ---------------------------------------------------------------------------
// K2: reduce Dep over NBLK partials -> de2 = 1/(De+eps)
// ---------------------------------------------------------------------------
__global__ __launch_bounds__(256) void k_dered(const float* __restrict__ Dep,
                                               float* __restrict__ de2) {
    const int g = blockIdx.x * 256 + threadIdx.x;
    if (g >= R * EE) return;
    const int r = g / EE, e = g - r * EE;
    const float* p = Dep + (size_t)r * NBLK * EE + e;
    float s = 0.f;
    for (int b = 0; b < NBLK; ++b) s += p[(size_t)b * EE];
    de2[g] = 1.0f / (s + EPSV);
}

// ---------------------------------------------------------------------------
// K3: Xbtd[r][f][n] = bf16( dv_r[n] * X[n][f] )   (transposed, dv folded)
// ---------------------------------------------------------------------------
__global__ __launch_bounds__(256) void k_xt(const float* __restrict__ X,
                                            const float* __restrict__ dv_is,
                                            unsigned short* __restrict__ Xbtd) {
    const int n0 = blockIdx.x * 64;
    const int f0 = blockIdx.y * 64;
    __shared__ float tile[64][65];
    __shared__ float dvt[4][64];
    const int t = threadIdx.x;
    {
        int nl = t >> 2, fl = (t & 3) * 16;
        int n = n0 + nl;
#pragma unroll
        for (int c = 0; c < 4; ++c) {
            float4 v = make_float4(0.f, 0.f, 0.f, 0.f);
            if (n < NN) v = *(const float4*)(X + (size_t)n * FF + f0 + fl + 4 * c);
            tile[nl][fl + 4 * c + 0] = v.x;
            tile[nl][fl + 4 * c + 1] = v.y;
            tile[nl][fl + 4 * c + 2] = v.z;
            tile[nl][fl + 4 * c + 3] = v.w;
        }
    }
    {
        int rr = t >> 6, nl = t & 63;
        int n = n0 + nl;
        dvt[rr][nl] = (n < NN) ? dv_is[rr * NN + n] : 0.f;
    }
    __syncthreads();
    const int fr = t >> 2, nc = (t & 3) * 16;
    for (int r = 0; r < R; ++r) {
        unsigned short u[16];
#pragma unroll
        for (int k = 0; k < 16; ++k)
            u[k] = f2bf(tile[nc + k][fr] * dvt[r][nc + k]);
        const int nb = n0 + nc;
        unsigned short* dst = Xbtd + (size_t)(r * FF + f0 + fr) * NN + nb;
        if (nb + 15 < NN) {
            uint4 p0, p1;
            p0.x = (unsigned)u[0]  | ((unsigned)u[1]  << 16);
            p0.y = (unsigned)u[2]  | ((unsigned)u[3]  << 16);
            p0.z = (unsigned)u[4]  | ((unsigned)u[5]  << 16);
            p0.w = (unsigned)u[6]  | ((unsigned)u[7]  << 16);
            p1.x = (unsigned)u[8]  | ((unsigned)u[9]  << 16);
            p1.y = (unsigned)u[10] | ((unsigned)u[11] << 16);
            p1.z = (unsigned)u[12] | ((unsigned)u[13] << 16);
            p1.w = (unsigned)u[14] | ((unsigned)u[15] << 16);
            *(uint4*)(dst)     = p0;
            *(uint4*)(dst + 8) = p1;
        } else {
#pragma unroll
            for (int k = 0; k < 16; ++k)
                if (nb + k < NN) dst[k] = u[k];
        }
    }
}

// ---------------------------------------------------------------------------
// K4 GEMM1: T2[kz][r][e][f] = de2[r][e] * sum_{n in kz-half} Hb[r][n][e] * Xbtd[r][f][n]
// BM=64 (e), BN=128 (f, 4 waves), BK=64 (n), 2-way K-split -> 256 blocks.
// ---------------------------------------------------------------------------
__global__ __launch_bounds__(256) void k_gemm1(const unsigned short* __restrict__ Hb,
                                               const unsigned short* __restrict__ Xbtd,
                                               const float* __restrict__ de2,
                                               float* __restrict__ T2) {
    const int e0 = blockIdx.x * 64;
    const int r  = blockIdx.y;
    const int kz = blockIdx.z;
    __shared__ unsigned short lA[64 * 64];
    __shared__ unsigned short lB[128 * 64];
    char* lAb = (char*)lA;
    char* lBb = (char*)lB;

    const int t = threadIdx.x, wave = t >> 6, lane = t & 63;
    const unsigned short* Hr = Hb + (size_t)r * NN * EE;
    const unsigned short* Xr = Xbtd + (size_t)r * FF * NN;

    f32x4 acc[4][2];
#pragma unroll
    for (int m = 0; m < 4; ++m)
#pragma unroll
        for (int nf = 0; nf < 2; ++nf) acc[m][nf] = (f32x4){0.f, 0.f, 0.f, 0.f};

    const int q  = t & 15;          // A: e-quad (4q .. 4q+3)
    const int p0 = t >> 4;          // A: n-pair base (0..15)
    const int bo = t >> 1;          // B: f row 0..127
    const int bh = (t & 1) * 32;    // B: half of 64 n
    const bool eok = (e0 + 4 * q) < EE;   // quad fully in-range (EE % 4 == 0)

    const int kbeg = kz * 5056;
    const int kend = (kbeg + 5056 < 10048) ? (kbeg + 5056) : 10048;

    for (int k0 = kbeg; k0 < kend; k0 += 64) {
        __syncthreads();
        // ---- stage A: repack 2 n-rows x 4 e into [e][n] bf16 pairs ----
#pragma unroll
        for (int h = 0; h < 2; ++h) {
            const int np = p0 + 16 * h;
            const int n_ = k0 + 2 * np;
            uint2 ha = make_uint2(0u, 0u), hb2 = make_uint2(0u, 0u);
            if (eok) {
                if (n_ < NN)     ha  = *(const uint2*)(Hr + (size_t)n_ * EE + e0 + 4 * q);
                if (n_ + 1 < NN) hb2 = *(const uint2*)(Hr + (size_t)(n_ + 1) * EE + e0 + 4 * q);
            }
            const unsigned a_[4] = {ha.x & 0xffffu, ha.x >> 16, ha.y & 0xffffu, ha.y >> 16};
            const unsigned b_[4] = {hb2.x & 0xffffu, hb2.x >> 16, hb2.y & 0xffffu, hb2.y >> 16};
#pragma unroll
            for (int j = 0; j < 4; ++j)
                *(unsigned*)(lAb + lds_addr(4 * q + j, 4 * np)) = a_[j] | (b_[j] << 16);
        }
        // ---- stage B: bf16 copy from Xbtd ----
#pragma unroll
        for (int j2 = 0; j2 < 4; ++j2) {
            const int nb = bh + 8 * j2;
            uint4 v = *(const uint4*)(Xr + (size_t)bo * NN + k0 + nb);
            *(uint4*)(lBb + lds_addr(bo, 2 * nb)) = v;
        }
        __syncthreads();
        // ---- MFMA ----
        {
            const int kb = (lane >> 4) * 16;
#pragma unroll
            for (int kk = 0; kk < 2; ++kk) {
                bf16x8 a[4], b[2];
#pragma unroll
                for (int m = 0; m < 4; ++m)
                    a[m] = *(const bf16x8*)(lAb + lds_addr((lane & 15) + 16 * m, kk * 64 + kb));
#pragma unroll
                for (int nf = 0; nf < 2; ++nf)
                    b[nf] = *(const bf16x8*)(lBb + lds_addr(wave * 32 + (lane & 15) + 16 * nf, kk * 64 + kb));
#pragma unroll
                for (int m = 0; m < 4; ++m)
#pragma unroll
                    for (int nf = 0; nf < 2; ++nf)
                        acc[m][nf] = __builtin_amdgcn_mfma_f32_16x16x32_bf16(
                            a[m], b[nf], acc[m][nf], 0, 0, 0);
            }
        }
    }
    // ---- epilogue: * de2, store T2 half ----
    float* Tz = T2 + (size_t)kz * R * EE * FF;
#pragma unroll
    for (int m = 0; m < 4; ++m) {
        const int eb = e0 + 16 * m + (lane >> 4) * 4;
#pragma unroll
        for (int j = 0; j < 4; ++j) {
            const int e = eb + j;
            if (e < EE) {
                const float s = de2[r * EE + e];
#pragma unroll
                for (int nf = 0; nf < 2; ++nf) {
                    const int f = wave * 32 + 16 * nf + (lane & 15);
                    Tz[((size_t)r * EE + e) * FF + f] = acc[m][nf][j] * s;
                }
            }
        }
    }
}

// ---------------------------------------------------------------------------
// K5: Vt[r][o][e] = bf16( sigmoid(ri[r]) * sum_f (T2[0]+T2[1])[r][e][f] * W[r][f][o] )
// ---------------------------------------------------------------------------
__global__ __launch_bounds__(256) void k_v(const float* __restrict__ T2,
                                           const float* __restrict__ W,
                                           const float* __restrict__ ri,
                                           unsigned short* __restrict__ Vt) {
    const int r  = blockIdx.y;
    const int e0 = blockIdx.x * 32;
    const float gate = 1.f / (1.f + expf(-ri[r]));
    __shared__ float lT[32][129];
    const int t = threadIdx.x;
    const size_t HALF = (size_t)R * EE * FF;
    {
        int el = t >> 3, fl = (t & 7) * 16;
        int e = e0 + el;
#pragma unroll
        for (int c = 0; c < 4; ++c) {
            float4 v = make_float4(0.f, 0.f, 0.f, 0.f);
            if (e < EE) {
                size_t idx = ((size_t)r * EE + e) * FF + fl + 4 * c;
                float4 v0 = *(const float4*)(T2 + idx);
                float4 v1 = *(const float4*)(T2 + HALF + idx);
                v.x = v0.x + v1.x; v.y = v0.y + v1.y;
                v.z = v0.z + v1.z; v.w = v0.w + v1.w;
            }
            lT[el][fl + 4 * c + 0] = v.x;
            lT[el][fl + 4 * c + 1] = v.y;
            lT[el][fl + 4 * c + 2] = v.z;
            lT[el][fl + 4 * c + 3] = v.w;
        }
    }
    __syncthreads();
    const int o  = t & 127;
    const int eh = t >> 7;
    float acc[16];
#pragma unroll
    for (int k = 0; k < 16; ++k) acc[k] = 0.f;
    const float* Wr = W + (size_t)r * FF * OO + o;
#pragma unroll 4
    for (int f = 0; f < FF; ++f) {
        float w = Wr[(size_t)f * OO];
#pragma unroll
        for (int k = 0; k < 16; ++k) acc[k] += lT[eh * 16 + k][f] * w;
    }
    const int ebase = e0 + eh * 16;
    unsigned short* dst = Vt + ((size_t)r * OO + o) * EE + ebase;
    if (ebase + 15 < EE) {
        unsigned short u[16];
#pragma unroll
        for (int k = 0; k < 16; ++k) u[k] = f2bf(gate * acc[k]);
        uint4 p0, p1;
        p0.x = (unsigned)u[0]  | ((unsigned)u[1]  << 16);
        p0.y = (unsigned)u[2]  | ((unsigned)u[3]  << 16);
        p0.z = (unsigned)u[4]  | ((unsigned)u[5]  << 16);
        p0.w = (unsigned)u[6]  | ((unsigned)u[7]  << 16);
        p1.x = (unsigned)u[8]  | ((unsigned)u[9]  << 16);
        p1.y = (unsigned)u[10] | ((unsigned)u[11] << 16);
        p1.z = (unsigned)u[12] | ((unsigned)u[13] << 16);
        p1.w = (unsigned)u[14] | ((unsigned)u[15] << 16);
        *(uint4*)(dst)     = p0;
        *(uint4*)(dst + 8) = p1;
    } else {
#pragma unroll
        for (int k = 0; k < 16; ++k)
            if (ebase + k < EE) dst[k] = f2bf(gate * acc[k]);
    }
}

// ---------------------------------------------------------------------------
// K6 GEMM2: outP[r][n][o] = dv_r[n] * sum_e Hb[r][n][e] * Vt[r][o][e]
// BM=64 (n), BN=128 (o, 4 waves), BK=64 (e); one r per block -> 628 blocks.
// ---------------------------------------------------------------------------
__global__ __launch_bounds__(256) void k_gemm2(const unsigned short* __restrict__ Hb,
                                               const unsigned short* __restrict__ Vt,
                                               const float* __restrict__ dv_is,
                                               float* __restrict__ outP) {
    const int n0 = blockIdx.x * 64;
    const int r  = blockIdx.y;
    __shared__ unsigned short lA[64 * 64];
    __shared__ unsigned short lB[128 * 64];
    char* lAb = (char*)lA;
    char* lBb = (char*)lB;

    const int t = threadIdx.x, wave = t >> 6, lane = t & 63;
    const unsigned short* Hr = Hb + (size_t)r * NN * EE;
    const unsigned short* Vr = Vt + (size_t)r * OO * EE;

    f32x4 acc[4][2];
#pragma unroll
    for (int m = 0; m < 4; ++m)
#pragma unroll
        for (int nf = 0; nf < 2; ++nf) acc[m][nf] = (f32x4){0.f, 0.f, 0.f, 0.f};

    const int nl = t >> 2;          // A: n-local row 0..63
    const int eo = (t & 3) * 16;    // A: e offset within 64
    const int bo = t >> 1;          // B: o row 0..127
    const int bh = (t & 1) * 32;    // B: half of 64 e
    const int nrow = n0 + nl;
    const bool nok = nrow < NN;
    const unsigned short* Arow = Hr + (size_t)nrow * EE;

    for (int ek = 0; ek < 2048; ek += 64) {   // 32 steps covering E=2000
        __syncthreads();
        // ---- stage A: direct bf16 copy of Hb rows ----
#pragma unroll
        for (int h = 0; h < 2; ++h) {
            const int e = ek + eo + 8 * h;
            uint4 v = make_uint4(0u, 0u, 0u, 0u);
            if (nok && (e + 7) < EE) v = *(const uint4*)(Arow + e);
            *(uint4*)(lAb + lds_addr(nl, 2 * (eo + 8 * h))) = v;
        }
        // ---- stage B: bf16 copy from Vt ----
#pragma unroll
        for (int j2 = 0; j2 < 4; ++j2) {
            const int eb = bh + 8 * j2;
            uint4 v = *(const uint4*)(Vr + (size_t)bo * EE + ek + eb);
            *(uint4*)(lBb + lds_addr(bo, 2 * eb)) = v;
        }
        __syncthreads();
        // ---- MFMA ----
        {
            const int kb = (lane >> 4) * 16;
#pragma unroll
            for (int kk = 0; kk < 2; ++kk) {
                bf16x8 a[4], b[2];
#pragma unroll
                for (int m = 0; m < 4; ++m)
                    a[m] = *(const bf16x8*)(lAb + lds_addr((lane & 15) + 16 * m, kk * 64 + kb));
#pragma unroll
                for (int nf = 0; nf < 2; ++nf)
                    b[nf] = *(const bf16x8*)(lBb + lds_addr(wave * 32 + (lane & 15) + 16 * nf, kk * 64 + kb));
#pragma unroll
                for (int m = 0; m < 4; ++m)
#pragma unroll
                    for (int nf = 0; nf < 2; ++nf)
                        acc[m][nf] = __builtin_amdgcn_mfma_f32_16x16x32_bf16(
                            a[m], b[nf], acc[m][nf], 0, 0, 0);
            }
        }
    }
    // ---- epilogue: * dv, store partial ----
#pragma unroll
    for (int m = 0; m < 4; ++m) {
        const int nb = n0 + 16 * m + (lane >> 4) * 4;
#pragma unroll
        for (int j = 0; j < 4; ++j) {
            const int n = nb + j;
            if (n < NN) {
                const float dv = dv_is[r * NN + n];
#pragma unroll
                for (int nf = 0; nf < 2; ++nf) {
                    const int o = wave * 32 + 16 * nf + (lane & 15);
                    outP[((size_t)r * NN + n) * OO + o] = dv * acc[m][nf][j];
                }
            }
        }
    }
}

// ---------------------------------------------------------------------------
// K7: out[n][o] = bias[o] + sum_r outP[r][n][o]
// ---------------------------------------------------------------------------
__global__ __launch_bounds__(256) void k_fin(const float* __restrict__ outP,
                                             const float* __restrict__ bias,
                                             float* __restrict__ out) {
    const int g = blockIdx.x * 256 + threadIdx.x;   // float4 index; 320000 total
    const int o4 = g & 31, n = g >> 5;
    float4 s = ((const float4*)bias)[o4];
#pragma unroll
    for (int r = 0; r < R; ++r) {
        float4 v = ((const float4*)outP)[((size_t)r * NN + n) * 32 + o4];
        s.x += v.x; s.y += v.y; s.z += v.z; s.w += v.w;
    }
    ((float4*)out)[g] = s;
}

// ---------------------------------------------------------------------------
extern "C" void kernel_launch(void* const* d_in, const int* in_sizes, int n_in,
                              void* d_out, int out_size, void* d_ws, size_t ws_size,
                              hipStream_t stream) {
    const float* X    = (const float*)d_in[0];
    const float* H    = (const float*)d_in[1];
    const float* W    = (const float*)d_in[2];
    const float* ri   = (const float*)d_in[3];
    const float* bias = (const float*)d_in[4];
    float* out = (float*)d_out;

    char* ws = (char*)d_ws;
    size_t off = 0;
    auto alloc = [&](size_t bytes) {
        size_t o = off;
        off += (bytes + 1023) & ~(size_t)1023;
        return o;
    };
    unsigned short* Hb    = (unsigned short*)(ws + alloc((size_t)R * NN * EE * 2 + 4096));
    float*          dv_is = (float*)(ws + alloc((size_t)R * NN * 4));
    float*          de2   = (float*)(ws + alloc((size_t)R * EE * 4));
    float*          Dep   = (float*)(ws + alloc((size_t)R * NBLK * EE * 4));
    unsigned short* Xbtd  = (unsigned short*)(ws + alloc((size_t)R * FF * NN * 2 + 4096));
    float*          T2    = (float*)(ws + alloc((size_t)2 * R * EE * FF * 4));
    unsigned short* Vt    = (unsigned short*)(ws + alloc((size_t)R * OO * EE * 2 + 4096));
    float*          outP  = (float*)(ws + alloc((size_t)R * NN * OO * 4));

    hipLaunchKernelGGL(k_prep,  dim3(NBLK, R),     dim3(256), 0, stream, H, Hb, dv_is, Dep);
    hipLaunchKernelGGL(k_dered, dim3(32),          dim3(256), 0, stream, Dep, de2);
    hipLaunchKernelGGL(k_xt,    dim3(157, 2),      dim3(256), 0, stream, X, dv_is, Xbtd);
    hipLaunchKernelGGL(k_gemm1, dim3(32, R, 2),    dim3(256), 0, stream, Hb, Xbtd, de2, T2);
    hipLaunchKernelGGL(k_v,     dim3(63, R),       dim3(256), 0, stream, T2, W, ri, Vt);
    hipLaunchKernelGGL(k_gemm2, dim3(157, R),      dim3(256), 0, stream, Hb, Vt, dv_is, outP);
    hipLaunchKernelGGL(k_fin,   dim3(1250),        dim3(256), 0, stream, outP, bias, out);
}